// Round 9
// baseline (190.795 us; speedup 1.0000x reference)
//
#include <hip/hip_runtime.h>
#include <hip/hip_bf16.h>
#include <hip/hip_fp16.h>
#include <stdint.h>

// Problem constants (fixed by setup_inputs): B=2, S=4096, D=1024, H=16, Dh=64
#define EPS_CLIP 1e-5f

typedef int i32x4 __attribute__((ext_vector_type(4)));

__device__ __forceinline__ void gload_lds16(const void* g, void* l) {
  __builtin_amdgcn_global_load_lds(
      (const __attribute__((address_space(1))) unsigned int*)g,
      (__attribute__((address_space(3))) unsigned int*)l, 16, 0, 0);
}

// ---------------- per-weight sum(|w|): stage 1, fp64 deterministic --------
__global__ __launch_bounds__(256) void wsum_part_kernel(
    const float* __restrict__ w0, const float* __restrict__ w1,
    const float* __restrict__ w2, const float* __restrict__ w3,
    double* __restrict__ part) {
  int bid = blockIdx.x;              // 256 blocks: 4 weights x 64 slices
  int widx = bid >> 6, slice = bid & 63;
  const float* w = widx == 0 ? w0 : widx == 1 ? w1 : widx == 2 ? w2 : w3;
  const float4* src = (const float4*)w + slice * 4096;
  int tid = threadIdx.x;
  double s = 0.0;
#pragma unroll
  for (int i = 0; i < 16; ++i) {
    float4 v = src[tid + i * 256];
    s += (double)fabsf(v.x) + (double)fabsf(v.y) +
         (double)fabsf(v.z) + (double)fabsf(v.w);
  }
  for (int off = 32; off; off >>= 1) s += __shfl_down(s, off, 64);
  __shared__ double ls[4];
  int lane = tid & 63, wv = tid >> 6;
  if (!lane) ls[wv] = s;
  __syncthreads();
  if (tid == 0) part[bid] = ls[0] + ls[1] + ls[2] + ls[3];  // fixed slot
}

// ---------------- stage 2: fixed-order fp64 tree over the 64 partials -----
__global__ __launch_bounds__(256) void wsum_final_kernel(
    const double* __restrict__ part, double* __restrict__ wsum) {
  int tid = threadIdx.x;
  int wv = tid >> 6, lane = tid & 63;      // one wave per weight matrix
  double s = part[wv * 64 + lane];
  for (int off = 32; off; off >>= 1) s += __shfl_down(s, off, 64);
  if (!lane) wsum[wv] = s;
}

// ---------------- ternary weight quant -> int8 {-1,0,1}, fp64 decision ----
__global__ __launch_bounds__(256) void wquant_kernel(
    const float* __restrict__ w0, const float* __restrict__ w1,
    const float* __restrict__ w2, const float* __restrict__ w3,
    const double* __restrict__ wsum, char* __restrict__ tern) {
  int gid = blockIdx.x * 256 + threadIdx.x;
  for (int i = gid; i < 4 * 262144; i += gridDim.x * 256) {  // float4 units
    int widx = i >> 18;
    int off = i & 262143;
    const float* w = widx == 0 ? w0 : widx == 1 ? w1 : widx == 2 ? w2 : w3;
    double s = 1.0 / fmax(wsum[widx] * (1.0 / 1048576.0), (double)EPS_CLIP);
    float4 v = ((const float4*)w)[off];
    char4 q;
    q.x = (char)(int)fmin(fmax(rint((double)v.x * s), -1.0), 1.0);
    q.y = (char)(int)fmin(fmax(rint((double)v.y * s), -1.0), 1.0);
    q.z = (char)(int)fmin(fmax(rint((double)v.z * s), -1.0), 1.0);
    q.w = (char)(int)fmin(fmax(rint((double)v.w * s), -1.0), 1.0);
    ((char4*)tern)[i] = q;
  }
}

// ---------------- fused rmsnorm + per-token absmax int8 quant -> int8 -----
// one block per token; fp32 input (first application, on x)
__global__ __launch_bounds__(256) void actquant_kernel(
    const float* __restrict__ x, char* __restrict__ act,
    float* __restrict__ s_tok) {
  int m = blockIdx.x;
  int tid = threadIdx.x;
  float4 v = ((const float4*)(x + (size_t)m * 1024))[tid];
  float ss = v.x * v.x + v.y * v.y + v.z * v.z + v.w * v.w;
  float am = fmaxf(fmaxf(fabsf(v.x), fabsf(v.y)), fmaxf(fabsf(v.z), fabsf(v.w)));
  for (int off = 32; off; off >>= 1) {
    ss += __shfl_down(ss, off, 64);
    am = fmaxf(am, __shfl_down(am, off, 64));
  }
  __shared__ float red[8];
  int lane = tid & 63, wv = tid >> 6;
  if (!lane) { red[wv] = ss; red[4 + wv] = am; }
  __syncthreads();
  if (tid == 0) {
    float sst = red[0] + red[1] + red[2] + red[3];
    float amt = fmaxf(fmaxf(red[4], red[5]), fmaxf(red[6], red[7]));
    float r = 1.0f / sqrtf(sst * (1.0f / 1024.0f) + 1e-6f);  // rmsnorm eps 1e-6
    float a = amt * r;                                        // max|y| (monotone)
    float s = 127.0f / fmaxf(a, EPS_CLIP);
    red[0] = r; red[1] = s;
    s_tok[m] = s;
  }
  __syncthreads();
  float r = red[0], s = red[1];
  // replicate reference rounding order: y = fl(x*r); q = rint(fl(y*s))
  char4 q;
  q.x = (char)(int)fminf(fmaxf(rintf((v.x * r) * s), -128.f), 127.f);
  q.y = (char)(int)fminf(fmaxf(rintf((v.y * r) * s), -128.f), 127.f);
  q.z = (char)(int)fminf(fmaxf(rintf((v.z * r) * s), -128.f), 127.f);
  q.w = (char)(int)fminf(fmaxf(rintf((v.w * r) * s), -128.f), 127.f);
  ((char4*)(act + (size_t)m * 1024))[tid] = q;
}

// ---------------- i8 GEMM, out[m,e] = sum_d A[m,d]*W[e,d], + scale --------
// 128x128 tile, BK=64, 4 waves (2x2), 4x4 16x16x64 i8 frags (m97 structure)
template <int OUT_MODE>   // 0: fp16 store (qkv), 1: f32 store (d_out)
__global__ __launch_bounds__(256) void gemm_i8_kernel(
    const char* __restrict__ A,           // int8 acts [8192][1024]
    const char* __restrict__ ternbase,    // int8 tern [4][1024][1024]
    void* __restrict__ Cbase, const float* __restrict__ s_tok,
    const double* __restrict__ wsum, int wbase) {
  int bm = blockIdx.x;             // 0..63  (M blocks)
  int by = blockIdx.y;
  int widx = by >> 3;
  int nb = by & 7;
  const char* W =
      ternbase + ((size_t)(wbase + widx)) * 1048576 + (size_t)nb * 128 * 1024;
  float wsc = (float)fmax(wsum[wbase + widx] * (1.0 / 1048576.0),
                          (double)EPS_CLIP);

  __shared__ __align__(16) char As[128 * 64];
  __shared__ __align__(16) char Bs[128 * 64];
  int tid = threadIdx.x;
  int lane = tid & 63, wv = tid >> 6;
  int wr = wv >> 1, wc = wv & 1;

  i32x4 acc[4][4] = {};
  const char* Arow = A + (size_t)bm * 128 * 1024;

  for (int k0 = 0; k0 < 1024; k0 += 64) {
#pragma unroll
    for (int c = 0; c < 2; ++c) {
      int i = c * 256 + tid;
      int row = i >> 2, g = i & 3;           // 4x 16B chunks per 64B row
      gload_lds16(Arow + (size_t)row * 1024 + k0 + g * 16, As + i * 16);
      gload_lds16(W + (size_t)row * 1024 + k0 + g * 16, Bs + i * 16);
    }
    __syncthreads();
    i32x4 aF[4], bF[4];
    int g16 = (lane >> 4) * 16;
    int r16 = lane & 15;
#pragma unroll
    for (int f = 0; f < 4; ++f) {
      aF[f] = *(const i32x4*)(As + (wr * 64 + f * 16 + r16) * 64 + g16);
      bF[f] = *(const i32x4*)(Bs + (wc * 64 + f * 16 + r16) * 64 + g16);
    }
#pragma unroll
    for (int fm = 0; fm < 4; ++fm)
#pragma unroll
      for (int fn = 0; fn < 4; ++fn)
        acc[fm][fn] = __builtin_amdgcn_mfma_i32_16x16x64_i8(
            aF[fm], bF[fn], acc[fm][fn], 0, 0, 0);
    __syncthreads();
  }
  // epilogue: C/D layout col=lane&15, row=(lane>>4)*4+j  (m89-verified)
  int col0 = nb * 128 + wc * 64 + (lane & 15);
  int row0 = bm * 128 + wr * 64 + (lane >> 4) * 4;
#pragma unroll
  for (int fm = 0; fm < 4; ++fm) {
#pragma unroll
    for (int j = 0; j < 4; ++j) {
      int row = row0 + fm * 16 + j;
      float dq = wsc / s_tok[row];   // int_sum * mean|w| / s_act
#pragma unroll
      for (int fn = 0; fn < 4; ++fn) {
        float val = (float)acc[fm][fn][j] * dq;   // int32 exact in fp32
        if constexpr (OUT_MODE == 0) {
          __half* C = (__half*)Cbase + (size_t)widx * 8192 * 1024;
          C[(size_t)row * 1024 + col0 + fn * 16] = __float2half(val);
        } else {
          float* C = (float*)Cbase;
          C[(size_t)row * 1024 + col0 + fn * 16] = val;
        }
      }
    }
  }
}

// ---- fused 16-token attention + ctx rmsnorm + int8 quant ----------------
// block g handles tokens m = g*16 + tok, tok=0..15 (same b, same s/16=sg).
// These 16 tokens x 16 heads form EXACTLY 16 complete rows of the permuted
// ctx matrix (row p = b*4096 + h*256 + sg, col = tok*64 + d), so the
// BitLinear pre-quant (rmsnorm + absmax int8) fuses in-register.
// Thread (h=tid>>4, t=tid&15): scores for (h,*), ctx cols t*4..t*4+3.
__global__ __launch_bounds__(256) void attn16_kernel(
    const __half* __restrict__ qkv, char* __restrict__ act,
    float* __restrict__ s_tok) {
  int g = blockIdx.x;                 // 0..511
  int tid = threadIdx.x;
  int h = tid >> 4, t = tid & 15;
  // 68-float row pitch: all four access patterns hit the 32-bank minimum
  __shared__ float qs[2][16 * 68];
  __shared__ float ks[2][16 * 68];
  __shared__ float vs[2][16 * 68];
  size_t base = (size_t)g * 16 * 1024;
  const __half* Q = qkv + base;
  const __half* K = qkv + 8388608 + base;
  const __half* V = qkv + 16777216 + base;
  int ldoff = (tid >> 4) * 68 + (tid & 15) * 4;   // staging slot

  float c[16][4];
#pragma unroll
  for (int i = 0; i < 16; ++i)
    c[i][0] = c[i][1] = c[i][2] = c[i][3] = 0.f;

  // prologue: stage token 0 into buf 0
  ushort4 qu = ((const ushort4*)Q)[tid];
  ushort4 ku = ((const ushort4*)K)[tid];
  ushort4 vu = ((const ushort4*)V)[tid];
  {
    float4 qf = make_float4(__half2float(*(__half*)&qu.x), __half2float(*(__half*)&qu.y),
                            __half2float(*(__half*)&qu.z), __half2float(*(__half*)&qu.w));
    float4 kf = make_float4(__half2float(*(__half*)&ku.x), __half2float(*(__half*)&ku.y),
                            __half2float(*(__half*)&ku.z), __half2float(*(__half*)&ku.w));
    float4 vf = make_float4(__half2float(*(__half*)&vu.x), __half2float(*(__half*)&vu.y),
                            __half2float(*(__half*)&vu.z), __half2float(*(__half*)&vu.w));
    *(float4*)&qs[0][ldoff] = qf;
    *(float4*)&ks[0][ldoff] = kf;
    *(float4*)&vs[0][ldoff] = vf;
  }

#pragma unroll
  for (int tok = 0; tok < 16; ++tok) {
    const int cur = tok & 1;
    if (tok < 15) {   // issue-early: next token's global loads (T14)
      qu = ((const ushort4*)(Q + (tok + 1) * 1024))[tid];
      ku = ((const ushort4*)(K + (tok + 1) * 1024))[tid];
      vu = ((const ushort4*)(V + (tok + 1) * 1024))[tid];
    }
    __syncthreads();                 // buf[cur] ready; prev readers done
    // ---- scores: sc(h,t) = q[h,:].k[t,:] / 8, float4 LDS reads
    float sc = 0.f;
    const float* qr = &qs[cur][h * 68];
    const float* kr = &ks[cur][t * 68];
#pragma unroll
    for (int d4 = 0; d4 < 16; ++d4) {
      float4 a = *(const float4*)(qr + d4 * 4);
      float4 b = *(const float4*)(kr + d4 * 4);
      sc += a.x * b.x + a.y * b.y + a.z * b.z + a.w * b.w;
    }
    sc *= 0.125f;                    // 1/sqrt(64), exact
    float mx = sc;
    for (int o = 8; o; o >>= 1) mx = fmaxf(mx, __shfl_xor(mx, o, 16));
    float e = __expf(sc - mx);
    float sum = e;
    for (int o = 8; o; o >>= 1) sum += __shfl_xor(sum, o, 16);
    float p = e / sum;
    // ---- PV: aw(h,tt) broadcast via in-wave shuffle (h-group is intra-wave)
    const float* vb = &vs[cur][t * 4];
    int gb = tid & 48;               // lane base of this h-group in the wave
#pragma unroll
    for (int tt = 0; tt < 16; ++tt) {
      float w = __shfl(p, gb | tt, 64);
      float4 vv = *(const float4*)(vb + tt * 68);
      c[tok][0] += w * vv.x; c[tok][1] += w * vv.y;
      c[tok][2] += w * vv.z; c[tok][3] += w * vv.w;
    }
    if (tok < 15) {  // write-late into the other buffer (WAR-safe: barrier above)
      const int nxt = cur ^ 1;
      float4 qf = make_float4(__half2float(*(__half*)&qu.x), __half2float(*(__half*)&qu.y),
                              __half2float(*(__half*)&qu.z), __half2float(*(__half*)&qu.w));
      float4 kf = make_float4(__half2float(*(__half*)&ku.x), __half2float(*(__half*)&ku.y),
                              __half2float(*(__half*)&ku.z), __half2float(*(__half*)&ku.w));
      float4 vf = make_float4(__half2float(*(__half*)&vu.x), __half2float(*(__half*)&vu.y),
                              __half2float(*(__half*)&vu.z), __half2float(*(__half*)&vu.w));
      *(float4*)&qs[nxt][ldoff] = qf;
      *(float4*)&ks[nxt][ldoff] = kf;
      *(float4*)&vs[nxt][ldoff] = vf;
    }
  }

  // ---- fused rmsnorm + absmax int8 quant over output row p (in-register)
  float ss = 0.f, am = 0.f;
#pragma unroll
  for (int tok = 0; tok < 16; ++tok)
#pragma unroll
    for (int i = 0; i < 4; ++i) {
      ss += c[tok][i] * c[tok][i];
      am = fmaxf(am, fabsf(c[tok][i]));
    }
  for (int o = 8; o; o >>= 1) {      // reduce across the 16-thread h-group
    ss += __shfl_xor(ss, o, 16);
    am = fmaxf(am, __shfl_xor(am, o, 16));
  }
  float r = 1.0f / sqrtf(ss * (1.0f / 1024.0f) + 1e-6f);
  float s = 127.0f / fmaxf(am * r, EPS_CLIP);
  int b = g >> 8, sg = g & 255;
  int p_row = (b << 12) + (h << 8) + sg;
  if (t == 0) s_tok[p_row] = s;
  char* dst = act + (size_t)p_row * 1024 + t * 4;
#pragma unroll
  for (int tok = 0; tok < 16; ++tok) {
    char4 q4;
    q4.x = (char)(int)fminf(fmaxf(rintf((c[tok][0] * r) * s), -128.f), 127.f);
    q4.y = (char)(int)fminf(fmaxf(rintf((c[tok][1] * r) * s), -128.f), 127.f);
    q4.z = (char)(int)fminf(fmaxf(rintf((c[tok][2] * r) * s), -128.f), 127.f);
    q4.w = (char)(int)fminf(fmaxf(rintf((c[tok][3] * r) * s), -128.f), 127.f);
    *(char4*)(dst + tok * 64) = q4;
  }
}

// --------------------------------------------------------------------------
extern "C" void kernel_launch(void* const* d_in, const int* in_sizes, int n_in,
                              void* d_out, int out_size, void* d_ws,
                              size_t ws_size, hipStream_t stream) {
  const float* x  = (const float*)d_in[0];
  const float* wq = (const float*)d_in[1];
  const float* wk = (const float*)d_in[2];
  const float* wv = (const float*)d_in[3];
  const float* wo = (const float*)d_in[4];
  float* out = (float*)d_out;

  char* ws = (char*)d_ws;
  // layout: tern i8  [4][1024][1024]  @0       (4 MB)
  //         act  i8  [8192][1024]     @4 MB    (8 MB)
  //         qkv  f16 [3][8192][1024]  @12 MB   (48 MB)
  //         s_tok f32 [8192]          @60 MB
  //         wsum f64 [8] + part f64[256] after
  char* tern = ws;
  char* act  = ws + ((size_t)4 << 20);
  __half* qkv = (__half*)(ws + ((size_t)12 << 20));
  float* s_tok = (float*)(ws + ((size_t)60 << 20));
  double* wsum = (double*)(ws + ((size_t)60 << 20) + 32768);
  double* part = wsum + 8;

  wsum_part_kernel<<<dim3(256), dim3(256), 0, stream>>>(wq, wk, wv, wo, part);
  wsum_final_kernel<<<dim3(1), dim3(256), 0, stream>>>(part, wsum);
  wquant_kernel<<<dim3(1024), dim3(256), 0, stream>>>(wq, wk, wv, wo, wsum, tern);
  actquant_kernel<<<dim3(8192), dim3(256), 0, stream>>>(x, act, s_tok);
  gemm_i8_kernel<0><<<dim3(64, 24), dim3(256), 0, stream>>>(act, tern, qkv,
                                                            s_tok, wsum, 0);
  attn16_kernel<<<dim3(512), dim3(256), 0, stream>>>(qkv, act, s_tok);
  gemm_i8_kernel<1><<<dim3(64, 8), dim3(256), 0, stream>>>(act, tern, out,
                                                           s_tok, wsum, 3);
}

// Round 10
// 184.575 us; speedup vs baseline: 1.0337x; 1.0337x over previous
//
#include <hip/hip_runtime.h>
#include <hip/hip_bf16.h>
#include <hip/hip_fp16.h>
#include <stdint.h>

// Problem constants (fixed by setup_inputs): B=2, S=4096, D=1024, H=16, Dh=64
#define EPS_CLIP 1e-5f

typedef int i32x4 __attribute__((ext_vector_type(4)));
typedef _Float16 hf2 __attribute__((ext_vector_type(2)));

__device__ __forceinline__ void gload_lds16(const void* g, void* l) {
  __builtin_amdgcn_global_load_lds(
      (const __attribute__((address_space(1))) unsigned int*)g,
      (__attribute__((address_space(3))) unsigned int*)l, 16, 0, 0);
}

// ---------------- per-weight sum(|w|): stage 1, fp64 deterministic --------
__global__ __launch_bounds__(256) void wsum_part_kernel(
    const float* __restrict__ w0, const float* __restrict__ w1,
    const float* __restrict__ w2, const float* __restrict__ w3,
    double* __restrict__ part) {
  int bid = blockIdx.x;              // 256 blocks: 4 weights x 64 slices
  int widx = bid >> 6, slice = bid & 63;
  const float* w = widx == 0 ? w0 : widx == 1 ? w1 : widx == 2 ? w2 : w3;
  const float4* src = (const float4*)w + slice * 4096;
  int tid = threadIdx.x;
  double s = 0.0;
#pragma unroll
  for (int i = 0; i < 16; ++i) {
    float4 v = src[tid + i * 256];
    s += (double)fabsf(v.x) + (double)fabsf(v.y) +
         (double)fabsf(v.z) + (double)fabsf(v.w);
  }
  for (int off = 32; off; off >>= 1) s += __shfl_down(s, off, 64);
  __shared__ double ls[4];
  int lane = tid & 63, wv = tid >> 6;
  if (!lane) ls[wv] = s;
  __syncthreads();
  if (tid == 0) part[bid] = ls[0] + ls[1] + ls[2] + ls[3];  // fixed slot
}

// ---------------- stage 2: fixed-order fp64 tree over the 64 partials -----
__global__ __launch_bounds__(256) void wsum_final_kernel(
    const double* __restrict__ part, double* __restrict__ wsum) {
  int tid = threadIdx.x;
  int wv = tid >> 6, lane = tid & 63;      // one wave per weight matrix
  double s = part[wv * 64 + lane];
  for (int off = 32; off; off >>= 1) s += __shfl_down(s, off, 64);
  if (!lane) wsum[wv] = s;
}

// ---------------- ternary weight quant -> int8 {-1,0,1}, fp64 decision ----
__global__ __launch_bounds__(256) void wquant_kernel(
    const float* __restrict__ w0, const float* __restrict__ w1,
    const float* __restrict__ w2, const float* __restrict__ w3,
    const double* __restrict__ wsum, char* __restrict__ tern) {
  int gid = blockIdx.x * 256 + threadIdx.x;
  for (int i = gid; i < 4 * 262144; i += gridDim.x * 256) {  // float4 units
    int widx = i >> 18;
    int off = i & 262143;
    const float* w = widx == 0 ? w0 : widx == 1 ? w1 : widx == 2 ? w2 : w3;
    double s = 1.0 / fmax(wsum[widx] * (1.0 / 1048576.0), (double)EPS_CLIP);
    float4 v = ((const float4*)w)[off];
    char4 q;
    q.x = (char)(int)fmin(fmax(rint((double)v.x * s), -1.0), 1.0);
    q.y = (char)(int)fmin(fmax(rint((double)v.y * s), -1.0), 1.0);
    q.z = (char)(int)fmin(fmax(rint((double)v.z * s), -1.0), 1.0);
    q.w = (char)(int)fmin(fmax(rint((double)v.w * s), -1.0), 1.0);
    ((char4*)tern)[i] = q;
  }
}

// ---------------- fused rmsnorm + per-token absmax int8 quant -> int8 -----
// one block per token; IS_BF16: input row is bf16 (ushort), else fp32
template <bool IS_BF16>
__global__ __launch_bounds__(256) void actquant_kernel(
    const void* __restrict__ xin, char* __restrict__ act,
    float* __restrict__ s_tok) {
  int m = blockIdx.x;
  int tid = threadIdx.x;
  float4 v;
  if constexpr (IS_BF16) {
    ushort4 u = ((const ushort4*)((const unsigned short*)xin +
                                  (size_t)m * 1024))[tid];
    union { unsigned u; float f; } cx, cy, cz, cw;
    cx.u = (unsigned)u.x << 16; cy.u = (unsigned)u.y << 16;
    cz.u = (unsigned)u.z << 16; cw.u = (unsigned)u.w << 16;
    v = make_float4(cx.f, cy.f, cz.f, cw.f);
  } else {
    v = ((const float4*)((const float*)xin + (size_t)m * 1024))[tid];
  }
  float ss = v.x * v.x + v.y * v.y + v.z * v.z + v.w * v.w;
  float am = fmaxf(fmaxf(fabsf(v.x), fabsf(v.y)), fmaxf(fabsf(v.z), fabsf(v.w)));
  for (int off = 32; off; off >>= 1) {
    ss += __shfl_down(ss, off, 64);
    am = fmaxf(am, __shfl_down(am, off, 64));
  }
  __shared__ float red[8];
  int lane = tid & 63, wv = tid >> 6;
  if (!lane) { red[wv] = ss; red[4 + wv] = am; }
  __syncthreads();
  if (tid == 0) {
    float sst = red[0] + red[1] + red[2] + red[3];
    float amt = fmaxf(fmaxf(red[4], red[5]), fmaxf(red[6], red[7]));
    float r = 1.0f / sqrtf(sst * (1.0f / 1024.0f) + 1e-6f);  // rmsnorm eps 1e-6
    float a = amt * r;                                        // max|y| (monotone)
    float s = 127.0f / fmaxf(a, EPS_CLIP);
    red[0] = r; red[1] = s;
    s_tok[m] = s;
  }
  __syncthreads();
  float r = red[0], s = red[1];
  // replicate reference rounding order: y = fl(x*r); q = rint(fl(y*s))
  char4 q;
  q.x = (char)(int)fminf(fmaxf(rintf((v.x * r) * s), -128.f), 127.f);
  q.y = (char)(int)fminf(fmaxf(rintf((v.y * r) * s), -128.f), 127.f);
  q.z = (char)(int)fminf(fmaxf(rintf((v.z * r) * s), -128.f), 127.f);
  q.w = (char)(int)fminf(fmaxf(rintf((v.w * r) * s), -128.f), 127.f);
  ((char4*)(act + (size_t)m * 1024))[tid] = q;
}

// ---------------- i8 GEMM, out[m,e] = sum_d A[m,d]*W[e,d], + scale --------
// 128x128 tile, BK=64, 4 waves (2x2), 4x4 16x16x64 i8 frags (m97 structure)
template <int OUT_MODE>   // 0: fp16 store (qkv), 1: f32 store (d_out)
__global__ __launch_bounds__(256) void gemm_i8_kernel(
    const char* __restrict__ A,           // int8 acts [8192][1024]
    const char* __restrict__ ternbase,    // int8 tern [4][1024][1024]
    void* __restrict__ Cbase, const float* __restrict__ s_tok,
    const double* __restrict__ wsum, int wbase) {
  int bm = blockIdx.x;             // 0..63  (M blocks)
  int by = blockIdx.y;
  int widx = by >> 3;
  int nb = by & 7;
  const char* W =
      ternbase + ((size_t)(wbase + widx)) * 1048576 + (size_t)nb * 128 * 1024;
  float wsc = (float)fmax(wsum[wbase + widx] * (1.0 / 1048576.0),
                          (double)EPS_CLIP);

  __shared__ __align__(16) char As[128 * 64];
  __shared__ __align__(16) char Bs[128 * 64];
  int tid = threadIdx.x;
  int lane = tid & 63, wv = tid >> 6;
  int wr = wv >> 1, wc = wv & 1;

  i32x4 acc[4][4] = {};
  const char* Arow = A + (size_t)bm * 128 * 1024;

  for (int k0 = 0; k0 < 1024; k0 += 64) {
#pragma unroll
    for (int c = 0; c < 2; ++c) {
      int i = c * 256 + tid;
      int row = i >> 2, g = i & 3;           // 4x 16B chunks per 64B row
      gload_lds16(Arow + (size_t)row * 1024 + k0 + g * 16, As + i * 16);
      gload_lds16(W + (size_t)row * 1024 + k0 + g * 16, Bs + i * 16);
    }
    __syncthreads();
    i32x4 aF[4], bF[4];
    int g16 = (lane >> 4) * 16;
    int r16 = lane & 15;
#pragma unroll
    for (int f = 0; f < 4; ++f) {
      aF[f] = *(const i32x4*)(As + (wr * 64 + f * 16 + r16) * 64 + g16);
      bF[f] = *(const i32x4*)(Bs + (wc * 64 + f * 16 + r16) * 64 + g16);
    }
#pragma unroll
    for (int fm = 0; fm < 4; ++fm)
#pragma unroll
      for (int fn = 0; fn < 4; ++fn)
        acc[fm][fn] = __builtin_amdgcn_mfma_i32_16x16x64_i8(
            aF[fm], bF[fn], acc[fm][fn], 0, 0, 0);
    __syncthreads();
  }
  // epilogue: C/D layout col=lane&15, row=(lane>>4)*4+j  (m89-verified)
  int col0 = nb * 128 + wc * 64 + (lane & 15);
  int row0 = bm * 128 + wr * 64 + (lane >> 4) * 4;
#pragma unroll
  for (int fm = 0; fm < 4; ++fm) {
#pragma unroll
    for (int j = 0; j < 4; ++j) {
      int row = row0 + fm * 16 + j;
      float dq = wsc / s_tok[row];   // int_sum * mean|w| / s_act
#pragma unroll
      for (int fn = 0; fn < 4; ++fn) {
        float val = (float)acc[fm][fn][j] * dq;   // int32 exact in fp32
        if constexpr (OUT_MODE == 0) {
          __half* C = (__half*)Cbase + (size_t)widx * 8192 * 1024;
          C[(size_t)row * 1024 + col0 + fn * 16] = __float2half(val);
        } else {
          float* C = (float*)Cbase;
          C[(size_t)row * 1024 + col0 + fn * 16] = val;
        }
      }
    }
  }
}

// ---------------- per-position 16x16 head-mixing attention (v2) ----------
// 1 token/block (8192 blocks, full TLP). fp16 staged in LDS (half the bytes
// of the f32 version); scores via v_dot2_f32_f16; softmax + weight
// broadcast fully in-wave (h-group = 16 contiguous lanes); 1 barrier.
// ctx written bf16 in the swapaxes(1,2) scrambled layout.
__global__ __launch_bounds__(256) void attn_kernel(
    const __half* __restrict__ qkv, unsigned short* __restrict__ ctxp) {
  int m = blockIdx.x;                 // token = b*4096 + s
  int b = m >> 12, s = m & 4095;
  int tid = threadIdx.x;
  // pitch 72 halves = 144 B/row: 16B-aligned rows, 4-bank shift per row;
  // all read patterns <=2-way (free) -- hand-checked
  __shared__ __align__(16) unsigned short qs[16 * 72];
  __shared__ __align__(16) unsigned short ks[16 * 72];
  __shared__ __align__(16) unsigned short vs[16 * 72];
  size_t off = (size_t)m * 1024;
  {
    ushort4 qu = ((const ushort4*)(qkv + off))[tid];
    ushort4 ku = ((const ushort4*)(qkv + 8388608 + off))[tid];
    ushort4 vu = ((const ushort4*)(qkv + 16777216 + off))[tid];
    int r = tid >> 4, c = (tid & 15) * 4;
    *(ushort4*)&qs[r * 72 + c] = qu;
    *(ushort4*)&ks[r * 72 + c] = ku;
    *(ushort4*)&vs[r * 72 + c] = vu;
  }
  __syncthreads();
  int h = tid >> 4, t = tid & 15;
  // ---- score sc(h,t) = q[h,:].k[t,:] / 8 via packed f16 dot
  float sc = 0.f;
  const unsigned short* qr = qs + h * 72;
  const unsigned short* kr = ks + t * 72;
#pragma unroll
  for (int d8 = 0; d8 < 8; ++d8) {     // 8 halves per iter, 16B reads
    uint4 qa = *(const uint4*)(qr + d8 * 8);
    uint4 kb = *(const uint4*)(kr + d8 * 8);
    union { uint4 u; hf2 h[4]; } qh, kh;
    qh.u = qa; kh.u = kb;
#pragma unroll
    for (int i = 0; i < 4; ++i) {
#if __has_builtin(__builtin_amdgcn_fdot2)
      sc = __builtin_amdgcn_fdot2(qh.h[i], kh.h[i], sc, false);
#else
      sc += (float)qh.h[i].x * (float)kh.h[i].x +
            (float)qh.h[i].y * (float)kh.h[i].y;
#endif
    }
  }
  sc *= 0.125f;                        // 1/sqrt(64), exact
  float mx = sc;
  for (int o = 8; o; o >>= 1) mx = fmaxf(mx, __shfl_xor(mx, o, 16));
  float e = __expf(sc - mx);
  float sum = e;
  for (int o = 8; o; o >>= 1) sum += __shfl_xor(sum, o, 16);
  float p = e / sum;
  // ---- PV: thread (h,t) owns ctx cols t*4..t*4+3; weights via in-wave shfl
  int gb = tid & 48;                   // lane base of this h-group
  float4 acc = make_float4(0.f, 0.f, 0.f, 0.f);
  const unsigned short* vb = vs + t * 4;
#pragma unroll
  for (int tt = 0; tt < 16; ++tt) {
    float w = __shfl(p, gb | tt, 64);
    ushort4 vv = *(const ushort4*)(vb + tt * 72);   // 8B read
    acc.x += w * __half2float(*(__half*)&vv.x);
    acc.y += w * __half2float(*(__half*)&vv.y);
    acc.z += w * __half2float(*(__half*)&vv.z);
    acc.w += w * __half2float(*(__half*)&vv.w);
  }
  // permuted row p = b*4096 + h*256 + s/16 ; col = (s%16)*64 + t*4
  int prow = (b << 12) + (h << 8) + (s >> 4);
  int col = (s & 15) * 64 + t * 4;
  __hip_bfloat16 b0 = __float2bfloat16(acc.x);
  __hip_bfloat16 b1 = __float2bfloat16(acc.y);
  __hip_bfloat16 b2 = __float2bfloat16(acc.z);
  __hip_bfloat16 b3 = __float2bfloat16(acc.w);
  ushort4 o4 = make_ushort4(*(unsigned short*)&b0, *(unsigned short*)&b1,
                            *(unsigned short*)&b2, *(unsigned short*)&b3);
  *(ushort4*)(ctxp + (size_t)prow * 1024 + col) = o4;
}

// --------------------------------------------------------------------------
extern "C" void kernel_launch(void* const* d_in, const int* in_sizes, int n_in,
                              void* d_out, int out_size, void* d_ws,
                              size_t ws_size, hipStream_t stream) {
  const float* x  = (const float*)d_in[0];
  const float* wq = (const float*)d_in[1];
  const float* wk = (const float*)d_in[2];
  const float* wv = (const float*)d_in[3];
  const float* wo = (const float*)d_in[4];
  float* out = (float*)d_out;

  char* ws = (char*)d_ws;
  // layout: tern i8  [4][1024][1024]  @0       (4 MB)
  //         act  i8  [8192][1024]     @4 MB    (8 MB)
  //         qkv  f16 [3][8192][1024]  @12 MB   (48 MB)
  //         ctxp bf16[8192][1024]     @60 MB   (16 MB)
  //         s_tok f32 [8192]          @76 MB
  //         wsum f64 [8] + part f64[256] after
  char* tern = ws;
  char* act  = ws + ((size_t)4 << 20);
  __half* qkv = (__half*)(ws + ((size_t)12 << 20));
  unsigned short* ctxp = (unsigned short*)(ws + ((size_t)60 << 20));
  float* s_tok = (float*)(ws + ((size_t)76 << 20));
  double* wsum = (double*)(ws + ((size_t)76 << 20) + 32768);
  double* part = wsum + 8;

  wsum_part_kernel<<<dim3(256), dim3(256), 0, stream>>>(wq, wk, wv, wo, part);
  wsum_final_kernel<<<dim3(1), dim3(256), 0, stream>>>(part, wsum);
  wquant_kernel<<<dim3(1024), dim3(256), 0, stream>>>(wq, wk, wv, wo, wsum, tern);
  actquant_kernel<false><<<dim3(8192), dim3(256), 0, stream>>>(x, act, s_tok);
  gemm_i8_kernel<0><<<dim3(64, 24), dim3(256), 0, stream>>>(act, tern, qkv,
                                                            s_tok, wsum, 0);
  attn_kernel<<<dim3(8192), dim3(256), 0, stream>>>(qkv, ctxp);
  actquant_kernel<true><<<dim3(8192), dim3(256), 0, stream>>>(ctxp, act, s_tok);
  gemm_i8_kernel<1><<<dim3(64, 8), dim3(256), 0, stream>>>(act, tern, out,
                                                           s_tok, wsum, 3);
}